// Round 1
// baseline (295.542 us; speedup 1.0000x reference)
//
#include <hip/hip_runtime.h>

#define BATCH 8
#define CH    3
#define HDIM  512
#define WDIM  512
#define PLANE (HDIM * WDIM)

__global__ __launch_bounds__(256) void seesaw_fused(
    const float* __restrict__ x,   // [B,3,H,W]
    const float* __restrict__ w1,  // [8,3,3,3]
    const float* __restrict__ b1,  // [8]
    const float* __restrict__ w2,  // [3,9]
    const float* __restrict__ b2,  // [3]
    float* __restrict__ out)       // [B,3,H,W]
{
    __shared__ float sw1[216];
    __shared__ float sb1[8];
    __shared__ float sw2[27];
    __shared__ float sb2[3];
    int t = threadIdx.x;
    if (t < 216) sw1[t] = w1[t];
    if (t < 8)   sb1[t] = b1[t];
    if (t < 27)  sw2[t] = w2[t];
    if (t < 3)   sb2[t] = b2[t];
    __syncthreads();

    int gid = blockIdx.x * 256 + t;           // [0, 8*512*512)
    int j = gid & (WDIM - 1);
    int i = (gid >> 9) & (HDIM - 1);
    int b = gid >> 18;

    const float* xb = x + (size_t)b * CH * PLANE;

    // ---- 3x3 conv (pad=1) -> 8 pre-activations ----
    float acc[8];
#pragma unroll
    for (int e = 0; e < 8; e++) acc[e] = sb1[e];

#pragma unroll
    for (int di = 0; di < 3; di++) {
        int y = i + di - 1;
        if (y < 0 || y >= HDIM) continue;
#pragma unroll
        for (int dj = 0; dj < 3; dj++) {
            int xc = j + dj - 1;
            if (xc < 0 || xc >= WDIM) continue;
            size_t base = (size_t)y * WDIM + xc;
#pragma unroll
            for (int c = 0; c < 3; c++) {
                float v = xb[(size_t)c * PLANE + base];
#pragma unroll
                for (int e = 0; e < 8; e++)
                    acc[e] = fmaf(v, sw1[e * 27 + c * 9 + di * 3 + dj], acc[e]);
            }
        }
    }

    // ---- sigmoid -> offsets in (0,1) ----
    float s[8];
#pragma unroll
    for (int e = 0; e < 8; e++)
        s[e] = 1.0f / (1.0f + __expf(-acc[e]));

    // ---- 9 sample points, bilinear (zeros padding), grouped 1x1 conv ----
    const float inv511 = 1.0f / 511.0f;
    float bx = (float)i * inv511;   // feeds gx (reference swaps axes)
    float by = (float)j * inv511;   // feeds gy
    float og0 = 0.f, og1 = 0.f, og2 = 0.f;

#pragma unroll
    for (int p = 0; p < 9; p++) {
        float c0, c1;
        if (p < 4)       { c0 = s[2 * p];           c1 = s[2 * p + 1]; }
        else if (p == 4) { c0 = 0.f;                c1 = 0.f; }
        else             { c0 = 2.0f - s[2 * (p - 5)]; c1 = 2.0f - s[2 * (p - 5) + 1]; }

        float gxv = bx + c0;
        float gyv = by + c1;
        // ix = ((gx+1)*W - 1)*0.5 = gx*256 + 255.5  (W=H=512)
        float ixf = gxv * 256.0f + 255.5f;
        float iyf = gyv * 256.0f + 255.5f;
        float ix0f = floorf(ixf);
        float iy0f = floorf(iyf);
        float wx1 = ixf - ix0f, wy1 = iyf - iy0f;
        float wx0 = 1.f - wx1,  wy0 = 1.f - wy1;
        int ix0 = (int)ix0f, iy0 = (int)iy0f;

        float s0 = 0.f, s1 = 0.f, s2 = 0.f;  // per-channel sampled value
#pragma unroll
        for (int cy = 0; cy < 2; cy++) {
            int yc = iy0 + cy;
            if (yc < 0 || yc >= HDIM) continue;
            float wy = cy ? wy1 : wy0;
#pragma unroll
            for (int cx = 0; cx < 2; cx++) {
                int xcc = ix0 + cx;
                if (xcc < 0 || xcc >= WDIM) continue;
                float wgt = wy * (cx ? wx1 : wx0);
                size_t base = (size_t)yc * WDIM + xcc;
                s0 = fmaf(xb[base],             wgt, s0);
                s1 = fmaf(xb[PLANE + base],     wgt, s1);
                s2 = fmaf(xb[2 * PLANE + base], wgt, s2);
            }
        }

        // group g = p/3 consumes point p with weights w2[g, (p%3)*3 + c]
        int g  = p / 3;
        int k0 = (p % 3) * 3;
        float* og = (g == 0) ? &og0 : (g == 1) ? &og1 : &og2;
        *og = fmaf(s0, sw2[g * 9 + k0 + 0], *og);
        *og = fmaf(s1, sw2[g * 9 + k0 + 1], *og);
        *og = fmaf(s2, sw2[g * 9 + k0 + 2], *og);
    }

    // ---- bias + relu + store [B,3,H,W] ----
    size_t ob = (size_t)(b * 3) * PLANE + (size_t)i * WDIM + j;
    float v0 = og0 + sb2[0];
    float v1 = og1 + sb2[1];
    float v2 = og2 + sb2[2];
    out[ob]             = v0 > 0.f ? v0 : 0.f;
    out[ob + PLANE]     = v1 > 0.f ? v1 : 0.f;
    out[ob + 2 * PLANE] = v2 > 0.f ? v2 : 0.f;
}

extern "C" void kernel_launch(void* const* d_in, const int* in_sizes, int n_in,
                              void* d_out, int out_size, void* d_ws, size_t ws_size,
                              hipStream_t stream) {
    const float* x  = (const float*)d_in[0];
    const float* w1 = (const float*)d_in[1];
    const float* b1 = (const float*)d_in[2];
    const float* w2 = (const float*)d_in[3];
    const float* b2 = (const float*)d_in[4];
    float* out = (float*)d_out;

    int total = BATCH * HDIM * WDIM;           // 2,097,152
    int blocks = total / 256;                  // 8192
    seesaw_fused<<<blocks, 256, 0, stream>>>(x, w1, b1, w2, b2, out);
}

// Round 2
// 179.600 us; speedup vs baseline: 1.6456x; 1.6456x over previous
//
#include <hip/hip_runtime.h>

#define BATCH 8
#define CH    3
#define HDIM  512
#define WDIM  512
#define PLANE (HDIM * WDIM)

// ---------- repack: NCHW -> NHWC (padded to float4) in d_ws ----------
__global__ __launch_bounds__(256) void repack_nhwc4(
    const float* __restrict__ x,   // [B,3,H,W]
    float4* __restrict__ xp)       // [B,H,W] float4 (c0,c1,c2,0)
{
    int gid = blockIdx.x * 256 + threadIdx.x;       // pixel id, j fastest
    int b = gid >> 18;
    int pix = gid & (PLANE - 1);
    const float* xb = x + (size_t)b * CH * PLANE;
    float4 v;
    v.x = xb[pix];
    v.y = xb[PLANE + pix];
    v.z = xb[2 * PLANE + pix];
    v.w = 0.0f;
    xp[(size_t)gid] = v;
}

// ---------- fused main kernel, reads NHWC4 ----------
__global__ __launch_bounds__(256) void seesaw_fused_v2(
    const float4* __restrict__ xp, // [B,H,W] float4
    const float* __restrict__ w1,  // [8,3,3,3]
    const float* __restrict__ b1,  // [8]
    const float* __restrict__ w2,  // [3,9]
    const float* __restrict__ b2,  // [3]
    float* __restrict__ out)       // [B,3,H,W]
{
    __shared__ float sw1[216];
    __shared__ float sb1[8];
    __shared__ float sw2[27];
    __shared__ float sb2[3];
    int t = threadIdx.x;
    if (t < 216) sw1[t] = w1[t];
    if (t < 8)   sb1[t] = b1[t];
    if (t < 27)  sw2[t] = w2[t];
    if (t < 3)   sb2[t] = b2[t];
    __syncthreads();

    int gid = blockIdx.x * 256 + t;
    int j = gid & (WDIM - 1);
    int i = (gid >> 9) & (HDIM - 1);
    int b = gid >> 18;

    const float4* xb = xp + ((size_t)b << 18);

    // ---- 3x3 conv (pad=1) -> 8 pre-activations ----
    float acc[8];
#pragma unroll
    for (int e = 0; e < 8; e++) acc[e] = sb1[e];

#pragma unroll
    for (int di = 0; di < 3; di++) {
        int y = i + di - 1;
        if (y < 0 || y >= HDIM) continue;
#pragma unroll
        for (int dj = 0; dj < 3; dj++) {
            int xc = j + dj - 1;
            if (xc < 0 || xc >= WDIM) continue;
            float4 v = xb[(y << 9) + xc];
#pragma unroll
            for (int e = 0; e < 8; e++) {
                const float* we = &sw1[e * 27 + di * 3 + dj];
                acc[e] = fmaf(v.x, we[0],  acc[e]);
                acc[e] = fmaf(v.y, we[9],  acc[e]);
                acc[e] = fmaf(v.z, we[18], acc[e]);
            }
        }
    }

    // ---- sigmoid -> offsets in (0,1) ----
    float s[8];
#pragma unroll
    for (int e = 0; e < 8; e++)
        s[e] = 1.0f / (1.0f + __expf(-acc[e]));

    // ---- 9 sample points, bilinear (zeros padding), grouped 1x1 conv ----
    const float inv511 = 1.0f / 511.0f;
    float bx = (float)i * inv511;   // feeds gx (reference swaps axes)
    float by = (float)j * inv511;   // feeds gy
    float og0 = 0.f, og1 = 0.f, og2 = 0.f;

#pragma unroll
    for (int p = 0; p < 9; p++) {
        float c0, c1;
        if (p < 4)       { c0 = s[2 * p];              c1 = s[2 * p + 1]; }
        else if (p == 4) { c0 = 0.f;                   c1 = 0.f; }
        else             { c0 = 2.0f - s[2 * (p - 5)]; c1 = 2.0f - s[2 * (p - 5) + 1]; }

        float ixf = (bx + c0) * 256.0f + 255.5f;   // ((gx+1)*512-1)*0.5
        float iyf = (by + c1) * 256.0f + 255.5f;
        float ix0f = floorf(ixf);
        float iy0f = floorf(iyf);
        float wx1 = ixf - ix0f, wy1 = iyf - iy0f;
        float wx0 = 1.f - wx1,  wy0 = 1.f - wy1;
        int ix0 = (int)ix0f, iy0 = (int)iy0f;

        float s0 = 0.f, s1 = 0.f, s2 = 0.f;
        if (ix0 >= -1 && ix0 <= 511 && iy0 >= -1 && iy0 <= 511) {
#pragma unroll
            for (int cy = 0; cy < 2; cy++) {
                int yc = iy0 + cy;
                if (yc < 0 || yc >= HDIM) continue;
                float wy = cy ? wy1 : wy0;
#pragma unroll
                for (int cx = 0; cx < 2; cx++) {
                    int xcc = ix0 + cx;
                    if (xcc < 0 || xcc >= WDIM) continue;
                    float wgt = wy * (cx ? wx1 : wx0);
                    float4 v = xb[(yc << 9) + xcc];
                    s0 = fmaf(v.x, wgt, s0);
                    s1 = fmaf(v.y, wgt, s1);
                    s2 = fmaf(v.z, wgt, s2);
                }
            }
        }

        // group g = p/3 consumes point p with weights w2[g, (p%3)*3 + c]
        int g  = p / 3;
        int k0 = (p % 3) * 3;
        float* og = (g == 0) ? &og0 : (g == 1) ? &og1 : &og2;
        *og = fmaf(s0, sw2[g * 9 + k0 + 0], *og);
        *og = fmaf(s1, sw2[g * 9 + k0 + 1], *og);
        *og = fmaf(s2, sw2[g * 9 + k0 + 2], *og);
    }

    size_t ob = (size_t)(b * 3) * PLANE + (size_t)i * WDIM + j;
    float v0 = og0 + sb2[0];
    float v1 = og1 + sb2[1];
    float v2 = og2 + sb2[2];
    out[ob]             = v0 > 0.f ? v0 : 0.f;
    out[ob + PLANE]     = v1 > 0.f ? v1 : 0.f;
    out[ob + 2 * PLANE] = v2 > 0.f ? v2 : 0.f;
}

// ---------- fallback (round-1 kernel) if ws too small ----------
__global__ __launch_bounds__(256) void seesaw_fused_v1(
    const float* __restrict__ x, const float* __restrict__ w1,
    const float* __restrict__ b1, const float* __restrict__ w2,
    const float* __restrict__ b2, float* __restrict__ out)
{
    __shared__ float sw1[216]; __shared__ float sb1[8];
    __shared__ float sw2[27];  __shared__ float sb2[3];
    int t = threadIdx.x;
    if (t < 216) sw1[t] = w1[t];
    if (t < 8)   sb1[t] = b1[t];
    if (t < 27)  sw2[t] = w2[t];
    if (t < 3)   sb2[t] = b2[t];
    __syncthreads();
    int gid = blockIdx.x * 256 + t;
    int j = gid & (WDIM - 1);
    int i = (gid >> 9) & (HDIM - 1);
    int b = gid >> 18;
    const float* xb = x + (size_t)b * CH * PLANE;
    float acc[8];
#pragma unroll
    for (int e = 0; e < 8; e++) acc[e] = sb1[e];
#pragma unroll
    for (int di = 0; di < 3; di++) {
        int y = i + di - 1;
        if (y < 0 || y >= HDIM) continue;
#pragma unroll
        for (int dj = 0; dj < 3; dj++) {
            int xc = j + dj - 1;
            if (xc < 0 || xc >= WDIM) continue;
            size_t base = (size_t)y * WDIM + xc;
#pragma unroll
            for (int c = 0; c < 3; c++) {
                float v = xb[(size_t)c * PLANE + base];
#pragma unroll
                for (int e = 0; e < 8; e++)
                    acc[e] = fmaf(v, sw1[e * 27 + c * 9 + di * 3 + dj], acc[e]);
            }
        }
    }
    float s[8];
#pragma unroll
    for (int e = 0; e < 8; e++) s[e] = 1.0f / (1.0f + __expf(-acc[e]));
    const float inv511 = 1.0f / 511.0f;
    float bx = (float)i * inv511, by = (float)j * inv511;
    float og0 = 0.f, og1 = 0.f, og2 = 0.f;
#pragma unroll
    for (int p = 0; p < 9; p++) {
        float c0, c1;
        if (p < 4)       { c0 = s[2 * p];              c1 = s[2 * p + 1]; }
        else if (p == 4) { c0 = 0.f;                   c1 = 0.f; }
        else             { c0 = 2.0f - s[2 * (p - 5)]; c1 = 2.0f - s[2 * (p - 5) + 1]; }
        float ixf = (bx + c0) * 256.0f + 255.5f;
        float iyf = (by + c1) * 256.0f + 255.5f;
        float ix0f = floorf(ixf), iy0f = floorf(iyf);
        float wx1 = ixf - ix0f, wy1 = iyf - iy0f;
        float wx0 = 1.f - wx1,  wy0 = 1.f - wy1;
        int ix0 = (int)ix0f, iy0 = (int)iy0f;
        float s0 = 0.f, s1 = 0.f, s2 = 0.f;
#pragma unroll
        for (int cy = 0; cy < 2; cy++) {
            int yc = iy0 + cy;
            if (yc < 0 || yc >= HDIM) continue;
            float wy = cy ? wy1 : wy0;
#pragma unroll
            for (int cx = 0; cx < 2; cx++) {
                int xcc = ix0 + cx;
                if (xcc < 0 || xcc >= WDIM) continue;
                float wgt = wy * (cx ? wx1 : wx0);
                size_t base = (size_t)yc * WDIM + xcc;
                s0 = fmaf(xb[base],             wgt, s0);
                s1 = fmaf(xb[PLANE + base],     wgt, s1);
                s2 = fmaf(xb[2 * PLANE + base], wgt, s2);
            }
        }
        int g  = p / 3;
        int k0 = (p % 3) * 3;
        float* og = (g == 0) ? &og0 : (g == 1) ? &og1 : &og2;
        *og = fmaf(s0, sw2[g * 9 + k0 + 0], *og);
        *og = fmaf(s1, sw2[g * 9 + k0 + 1], *og);
        *og = fmaf(s2, sw2[g * 9 + k0 + 2], *og);
    }
    size_t ob = (size_t)(b * 3) * PLANE + (size_t)i * WDIM + j;
    float v0 = og0 + sb2[0], v1 = og1 + sb2[1], v2 = og2 + sb2[2];
    out[ob]             = v0 > 0.f ? v0 : 0.f;
    out[ob + PLANE]     = v1 > 0.f ? v1 : 0.f;
    out[ob + 2 * PLANE] = v2 > 0.f ? v2 : 0.f;
}

extern "C" void kernel_launch(void* const* d_in, const int* in_sizes, int n_in,
                              void* d_out, int out_size, void* d_ws, size_t ws_size,
                              hipStream_t stream) {
    const float* x  = (const float*)d_in[0];
    const float* w1 = (const float*)d_in[1];
    const float* b1 = (const float*)d_in[2];
    const float* w2 = (const float*)d_in[3];
    const float* b2 = (const float*)d_in[4];
    float* out = (float*)d_out;

    int total = BATCH * HDIM * WDIM;           // 2,097,152
    int blocks = total / 256;                  // 8192
    size_t need = (size_t)total * 4 * sizeof(float);  // 32 MiB NHWC4

    if (ws_size >= need) {
        float4* xp = (float4*)d_ws;
        repack_nhwc4<<<blocks, 256, 0, stream>>>(x, xp);
        seesaw_fused_v2<<<blocks, 256, 0, stream>>>(xp, w1, b1, w2, b2, out);
    } else {
        seesaw_fused_v1<<<blocks, 256, 0, stream>>>(x, w1, b1, w2, b2, out);
    }
}

// Round 3
// 158.541 us; speedup vs baseline: 1.8641x; 1.1328x over previous
//
#include <hip/hip_runtime.h>

#define BATCH 8
#define HDIM  512
#define WDIM  512
#define PLANE (HDIM * WDIM)

typedef _Float16 half4v __attribute__((ext_vector_type(4)));
typedef _Float16 half8v __attribute__((ext_vector_type(8)));

// ---------- repack: NCHW fp32 -> [B,H,W] half4 (c0,c1,c2,0), 16 MiB ----------
__global__ __launch_bounds__(256) void repack_h4(
    const float* __restrict__ x,   // [B,3,H,W]
    half8v* __restrict__ xp)       // [B*PLANE/2] pairs of half4
{
    int gid = blockIdx.x * 256 + threadIdx.x;   // 2-pixel unit id
    int b = gid >> 17;                          // PLANE/2 = 2^17 units per batch
    int u = gid & ((PLANE / 2) - 1);
    const float* xb = x + (size_t)b * 3 * PLANE;
    int pix = u * 2;
    float2 a0 = *(const float2*)(xb + pix);
    float2 a1 = *(const float2*)(xb + PLANE + pix);
    float2 a2 = *(const float2*)(xb + 2 * PLANE + pix);
    half8v o;
    o[0] = (_Float16)a0.x; o[1] = (_Float16)a1.x; o[2] = (_Float16)a2.x; o[3] = (_Float16)0.f;
    o[4] = (_Float16)a0.y; o[5] = (_Float16)a1.y; o[6] = (_Float16)a2.y; o[7] = (_Float16)0.f;
    xp[(size_t)gid] = o;
}

// ---------- main: conv(fp32 planar) + branchless 5-point gather (fp16 pack) ----------
__global__ __launch_bounds__(256, 4) void seesaw_v3(
    const float* __restrict__ x,     // [B,3,H,W] fp32 (for conv + mirror fallback)
    const half4v* __restrict__ xp,   // [B,H,W] half4
    const float* __restrict__ w1, const float* __restrict__ b1,
    const float* __restrict__ w2, const float* __restrict__ b2,
    float* __restrict__ out)
{
    __shared__ float sw1[216];
    __shared__ float sb1[8];
    __shared__ float sw2[27];
    __shared__ float sb2[3];
    int t = threadIdx.x;
    if (t < 216) sw1[t] = w1[t];
    if (t < 8)   sb1[t] = b1[t];
    if (t < 27)  sw2[t] = w2[t];
    if (t < 3)   sb2[t] = b2[t];
    __syncthreads();

    int gid = blockIdx.x * 256 + t;
    int j = gid & (WDIM - 1);
    int i = (gid >> 9) & (HDIM - 1);
    int b = gid >> 18;

    const float*  xb = x  + (size_t)b * 3 * PLANE;
    const half4v* hb = xp + ((size_t)b << 18);

    // ---- 3x3 conv (pad=1), fp32 planar reads -> 8 pre-activations ----
    float acc[8];
#pragma unroll
    for (int e = 0; e < 8; e++) acc[e] = sb1[e];

#pragma unroll
    for (int di = 0; di < 3; di++) {
        int y = i + di - 1;
        if (y < 0 || y >= HDIM) continue;
#pragma unroll
        for (int dj = 0; dj < 3; dj++) {
            int xc = j + dj - 1;
            if (xc < 0 || xc >= WDIM) continue;
            int base = (y << 9) + xc;
            float v0 = xb[base];
            float v1 = xb[PLANE + base];
            float v2 = xb[2 * PLANE + base];
#pragma unroll
            for (int e = 0; e < 8; e++) {
                const float* we = &sw1[e * 27 + di * 3 + dj];
                acc[e] = fmaf(v0, we[0],  acc[e]);
                acc[e] = fmaf(v1, we[9],  acc[e]);
                acc[e] = fmaf(v2, we[18], acc[e]);
            }
        }
    }

    // ---- sigmoid ----
    float s[8];
#pragma unroll
    for (int e = 0; e < 8; e++) {
        float ex = __expf(-acc[e]);
        s[e] = __builtin_amdgcn_rcpf(1.0f + ex);
    }

    const float inv511 = 1.0f / 511.0f;
    float bx = (float)i * inv511;   // feeds gx (reference swaps axes)
    float by = (float)j * inv511;   // feeds gy

    // ---- phase 1: coords, weights, clamped offsets for points 0..4 ----
    // points 0..3: offsets (s,s); point 4: center (0,0).
    // Low side never OOB (ixf > 255.49); only high side needs clamping.
    int   offs[5][4];
    float wts[5][4];
#pragma unroll
    for (int p = 0; p < 5; p++) {
        float c0 = (p < 4) ? s[2 * p]     : 0.0f;
        float c1 = (p < 4) ? s[2 * p + 1] : 0.0f;
        float ixf = fmaf(bx + c0, 256.0f, 255.5f);
        float iyf = fmaf(by + c1, 256.0f, 255.5f);
        float ix0f = floorf(ixf);
        float iy0f = floorf(iyf);
        float wx1 = ixf - ix0f, wy1 = iyf - iy0f;
        float wx0 = 1.f - wx1,  wy0 = 1.f - wy1;
        int ix0 = (int)ix0f, iy0 = (int)iy0f;

        float wx0v = (ix0 <= 511) ? wx0 : 0.f;
        float wx1v = (ix0 <= 510) ? wx1 : 0.f;
        float wy0v = (iy0 <= 511) ? wy0 : 0.f;
        float wy1v = (iy0 <= 510) ? wy1 : 0.f;
        int x0c = min(ix0, 511), x1c = min(ix0 + 1, 511);
        int y0c = min(iy0, 511), y1c = min(iy0 + 1, 511);

        float w00 = wy0v * wx0v, w01 = wy0v * wx1v;
        float w10 = wy1v * wx0v, w11 = wy1v * wx1v;
        int o00 = (y0c << 9) + x0c, o01 = (y0c << 9) + x1c;
        int o10 = (y1c << 9) + x0c, o11 = (y1c << 9) + x1c;
        // dead corners -> broadcast address 0 (no scattered transaction)
        wts[p][0] = w00; offs[p][0] = (w00 > 0.f) ? o00 : 0;
        wts[p][1] = w01; offs[p][1] = (w01 > 0.f) ? o01 : 0;
        wts[p][2] = w10; offs[p][2] = (w10 > 0.f) ? o10 : 0;
        wts[p][3] = w11; offs[p][3] = (w11 > 0.f) ? o11 : 0;
    }

    // ---- phase 2: all 20 loads, no control flow (max MLP) ----
    half4v vals[5][4];
#pragma unroll
    for (int p = 0; p < 5; p++)
#pragma unroll
        for (int c = 0; c < 4; c++)
            vals[p][c] = hb[offs[p][c]];

    // ---- phase 3: bilinear + grouped 1x1 accumulate ----
    float og[3] = {0.f, 0.f, 0.f};
#pragma unroll
    for (int p = 0; p < 5; p++) {
        float s0 = 0.f, s1 = 0.f, s2 = 0.f;
#pragma unroll
        for (int c = 0; c < 4; c++) {
            float w = wts[p][c];
            half4v v = vals[p][c];
            s0 = fmaf((float)v[0], w, s0);
            s1 = fmaf((float)v[1], w, s1);
            s2 = fmaf((float)v[2], w, s2);
        }
        int g  = p / 3;             // 0,0,0,1,1
        int k0 = (p % 3) * 3;
        og[g] = fmaf(s0, sw2[g * 9 + k0 + 0], og[g]);
        og[g] = fmaf(s1, sw2[g * 9 + k0 + 1], og[g]);
        og[g] = fmaf(s2, sw2[g * 9 + k0 + 2], og[g]);
    }

    // ---- mirror points p=5..8: provably only pixel (0,0) can contribute ----
    if ((i | j) == 0) {
#pragma unroll
        for (int p = 5; p < 9; p++) {
            float c0 = 2.0f - s[2 * (p - 5)];
            float c1 = 2.0f - s[2 * (p - 5) + 1];
            float ixf = fmaf(bx + c0, 256.0f, 255.5f);
            float iyf = fmaf(by + c1, 256.0f, 255.5f);
            float ix0f = floorf(ixf), iy0f = floorf(iyf);
            float wx1 = ixf - ix0f, wy1 = iyf - iy0f;
            float wx0 = 1.f - wx1,  wy0 = 1.f - wy1;
            int ix0 = (int)ix0f, iy0 = (int)iy0f;
            float s0 = 0.f, s1 = 0.f, s2 = 0.f;
            for (int cy = 0; cy < 2; cy++) {
                int yc = iy0 + cy;
                if (yc < 0 || yc >= HDIM) continue;
                float wy = cy ? wy1 : wy0;
                for (int cx = 0; cx < 2; cx++) {
                    int xcc = ix0 + cx;
                    if (xcc < 0 || xcc >= WDIM) continue;
                    float wgt = wy * (cx ? wx1 : wx0);
                    int base = (yc << 9) + xcc;
                    s0 = fmaf(xb[base],             wgt, s0);
                    s1 = fmaf(xb[PLANE + base],     wgt, s1);
                    s2 = fmaf(xb[2 * PLANE + base], wgt, s2);
                }
            }
            int g  = p / 3;
            int k0 = (p % 3) * 3;
            og[g] = fmaf(s0, sw2[g * 9 + k0 + 0], og[g]);
            og[g] = fmaf(s1, sw2[g * 9 + k0 + 1], og[g]);
            og[g] = fmaf(s2, sw2[g * 9 + k0 + 2], og[g]);
        }
    }

    size_t ob = (size_t)(b * 3) * PLANE + (size_t)i * WDIM + j;
    float v0 = og[0] + sb2[0];
    float v1 = og[1] + sb2[1];
    float v2 = og[2] + sb2[2];
    out[ob]             = v0 > 0.f ? v0 : 0.f;
    out[ob + PLANE]     = v1 > 0.f ? v1 : 0.f;
    out[ob + 2 * PLANE] = v2 > 0.f ? v2 : 0.f;
}

// ---------- fallback (round-1 kernel) if ws too small ----------
__global__ __launch_bounds__(256) void seesaw_fused_v1(
    const float* __restrict__ x, const float* __restrict__ w1,
    const float* __restrict__ b1, const float* __restrict__ w2,
    const float* __restrict__ b2, float* __restrict__ out)
{
    __shared__ float sw1[216]; __shared__ float sb1[8];
    __shared__ float sw2[27];  __shared__ float sb2[3];
    int t = threadIdx.x;
    if (t < 216) sw1[t] = w1[t];
    if (t < 8)   sb1[t] = b1[t];
    if (t < 27)  sw2[t] = w2[t];
    if (t < 3)   sb2[t] = b2[t];
    __syncthreads();
    int gid = blockIdx.x * 256 + t;
    int j = gid & (WDIM - 1);
    int i = (gid >> 9) & (HDIM - 1);
    int b = gid >> 18;
    const float* xb = x + (size_t)b * 3 * PLANE;
    float acc[8];
#pragma unroll
    for (int e = 0; e < 8; e++) acc[e] = sb1[e];
#pragma unroll
    for (int di = 0; di < 3; di++) {
        int y = i + di - 1;
        if (y < 0 || y >= HDIM) continue;
#pragma unroll
        for (int dj = 0; dj < 3; dj++) {
            int xc = j + dj - 1;
            if (xc < 0 || xc >= WDIM) continue;
            size_t base = (size_t)y * WDIM + xc;
#pragma unroll
            for (int c = 0; c < 3; c++) {
                float v = xb[(size_t)c * PLANE + base];
#pragma unroll
                for (int e = 0; e < 8; e++)
                    acc[e] = fmaf(v, sw1[e * 27 + c * 9 + di * 3 + dj], acc[e]);
            }
        }
    }
    float s[8];
#pragma unroll
    for (int e = 0; e < 8; e++) s[e] = 1.0f / (1.0f + __expf(-acc[e]));
    const float inv511 = 1.0f / 511.0f;
    float bx = (float)i * inv511, by = (float)j * inv511;
    float og0 = 0.f, og1 = 0.f, og2 = 0.f;
#pragma unroll
    for (int p = 0; p < 9; p++) {
        float c0, c1;
        if (p < 4)       { c0 = s[2 * p];              c1 = s[2 * p + 1]; }
        else if (p == 4) { c0 = 0.f;                   c1 = 0.f; }
        else             { c0 = 2.0f - s[2 * (p - 5)]; c1 = 2.0f - s[2 * (p - 5) + 1]; }
        float ixf = (bx + c0) * 256.0f + 255.5f;
        float iyf = (by + c1) * 256.0f + 255.5f;
        float ix0f = floorf(ixf), iy0f = floorf(iyf);
        float wx1 = ixf - ix0f, wy1 = iyf - iy0f;
        float wx0 = 1.f - wx1,  wy0 = 1.f - wy1;
        int ix0 = (int)ix0f, iy0 = (int)iy0f;
        float s0 = 0.f, s1 = 0.f, s2 = 0.f;
#pragma unroll
        for (int cy = 0; cy < 2; cy++) {
            int yc = iy0 + cy;
            if (yc < 0 || yc >= HDIM) continue;
            float wy = cy ? wy1 : wy0;
#pragma unroll
            for (int cx = 0; cx < 2; cx++) {
                int xcc = ix0 + cx;
                if (xcc < 0 || xcc >= WDIM) continue;
                float wgt = wy * (cx ? wx1 : wx0);
                size_t base = (size_t)yc * WDIM + xcc;
                s0 = fmaf(xb[base],             wgt, s0);
                s1 = fmaf(xb[PLANE + base],     wgt, s1);
                s2 = fmaf(xb[2 * PLANE + base], wgt, s2);
            }
        }
        int g  = p / 3;
        int k0 = (p % 3) * 3;
        float* og = (g == 0) ? &og0 : (g == 1) ? &og1 : &og2;
        *og = fmaf(s0, sw2[g * 9 + k0 + 0], *og);
        *og = fmaf(s1, sw2[g * 9 + k0 + 1], *og);
        *og = fmaf(s2, sw2[g * 9 + k0 + 2], *og);
    }
    size_t ob = (size_t)(b * 3) * PLANE + (size_t)i * WDIM + j;
    float v0 = og0 + sb2[0], v1 = og1 + sb2[1], v2 = og2 + sb2[2];
    out[ob]             = v0 > 0.f ? v0 : 0.f;
    out[ob + PLANE]     = v1 > 0.f ? v1 : 0.f;
    out[ob + 2 * PLANE] = v2 > 0.f ? v2 : 0.f;
}

extern "C" void kernel_launch(void* const* d_in, const int* in_sizes, int n_in,
                              void* d_out, int out_size, void* d_ws, size_t ws_size,
                              hipStream_t stream) {
    const float* x  = (const float*)d_in[0];
    const float* w1 = (const float*)d_in[1];
    const float* b1 = (const float*)d_in[2];
    const float* w2 = (const float*)d_in[3];
    const float* b2 = (const float*)d_in[4];
    float* out = (float*)d_out;

    int total = BATCH * HDIM * WDIM;                 // 2,097,152
    size_t need = (size_t)total * 8;                 // 16 MiB fp16x4 pack

    if (ws_size >= need) {
        half8v* xp = (half8v*)d_ws;
        repack_h4<<<total / 2 / 256, 256, 0, stream>>>(x, xp);
        seesaw_v3<<<total / 256, 256, 0, stream>>>(x, (const half4v*)d_ws,
                                                   w1, b1, w2, b2, out);
    } else {
        seesaw_fused_v1<<<total / 256, 256, 0, stream>>>(x, w1, b1, w2, b2, out);
    }
}

// Round 4
// 139.112 us; speedup vs baseline: 2.1245x; 1.1397x over previous
//
#include <hip/hip_runtime.h>

#define BATCH 8
#define HDIM  512
#define WDIM  512
#define PLANE (HDIM * WDIM)

typedef _Float16 half4v __attribute__((ext_vector_type(4)));
typedef _Float16 half8v __attribute__((ext_vector_type(8)));

struct __align__(8) HPair { half4v lo, hi; };   // two adjacent texels, 16B

// ---------- repack: NCHW fp32 -> [B,H,W] half4 (c0,c1,c2,0), 16 MiB ----------
__global__ __launch_bounds__(256) void repack_h4(
    const float* __restrict__ x,   // [B,3,H,W]
    half8v* __restrict__ xp)       // [B*PLANE/2] pairs of half4
{
    int gid = blockIdx.x * 256 + threadIdx.x;   // 2-pixel unit id
    int b = gid >> 17;
    int u = gid & ((PLANE / 2) - 1);
    const float* xb = x + (size_t)b * 3 * PLANE;
    int pix = u * 2;
    float2 a0 = *(const float2*)(xb + pix);
    float2 a1 = *(const float2*)(xb + PLANE + pix);
    float2 a2 = *(const float2*)(xb + 2 * PLANE + pix);
    half8v o;
    o[0] = (_Float16)a0.x; o[1] = (_Float16)a1.x; o[2] = (_Float16)a2.x; o[3] = (_Float16)0.f;
    o[4] = (_Float16)a0.y; o[5] = (_Float16)a1.y; o[6] = (_Float16)a2.y; o[7] = (_Float16)0.f;
    xp[(size_t)gid] = o;
}

// 5-point gather + grouped accumulate for one pixel.
// s: 8 sigmoids; bx feeds gx (row-based, reference swaps axes); by feeds gy.
__device__ __forceinline__ void gather5(
    const half4v* __restrict__ hb, const float* __restrict__ w2,
    const float s[8], float bx, float by, float og[3])
{
    int   adr[5][2];
    float wY[5][2], wX0[5], wX1[5];
#pragma unroll
    for (int q = 0; q < 5; q++) {
        float c0 = (q < 4) ? s[2 * q]     : 0.0f;
        float c1 = (q < 4) ? s[2 * q + 1] : 0.0f;
        float ixf = fmaf(bx + c0, 256.0f, 255.5f);   // ((gx+1)*512-1)*0.5
        float iyf = fmaf(by + c1, 256.0f, 255.5f);
        float ix0f = floorf(ixf);
        float iy0f = floorf(iyf);
        float wx1 = ixf - ix0f, wy1 = iyf - iy0f;
        float wx0 = 1.f - wx1,  wy0 = 1.f - wy1;
        int ix0 = (int)ix0f, iy0 = (int)iy0f;       // low side never <0 (ixf>255.4)

        float wx0v = (ix0 <= 511) ? wx0 : 0.f;
        float wx1v = (ix0 <= 510) ? wx1 : 0.f;
        float wy0v = (iy0 <= 511) ? wy0 : 0.f;
        float wy1v = (iy0 <= 510) ? wy1 : 0.f;
        int x0c = min(ix0, 511);
        int y0c = min(iy0, 511), y1c = min(iy0 + 1, 511);

        float wxs = wx0v + wx1v;
        wX0[q] = wx0v; wX1[q] = wx1v;
        wY[q][0] = wy0v; wY[q][1] = wy1v;
        // dead rows -> broadcast address 0 (single line, no scatter)
        adr[q][0] = (wy0v * wxs > 0.f) ? ((y0c << 9) + x0c) : 0;
        adr[q][1] = (wy1v * wxs > 0.f) ? ((y1c << 9) + x0c) : 0;
    }

    // all 10 pair-loads back-to-back (max MLP)
    HPair pv[5][2];
#pragma unroll
    for (int q = 0; q < 5; q++) {
        pv[q][0] = *(const HPair*)(hb + adr[q][0]);
        pv[q][1] = *(const HPair*)(hb + adr[q][1]);
    }

#pragma unroll
    for (int q = 0; q < 5; q++) {
        float sc[3];
#pragma unroll
        for (int c = 0; c < 3; c++) {
            float r0 = fmaf((float)pv[q][0].hi[c], wX1[q], (float)pv[q][0].lo[c] * wX0[q]);
            float r1 = fmaf((float)pv[q][1].hi[c], wX1[q], (float)pv[q][1].lo[c] * wX0[q]);
            sc[c] = fmaf(r1, wY[q][1], r0 * wY[q][0]);
        }
        int g  = q / 3;            // 0,0,0,1,1
        int k0 = (q % 3) * 3;
        og[g] = fmaf(sc[0], w2[g * 9 + k0 + 0], og[g]);
        og[g] = fmaf(sc[1], w2[g * 9 + k0 + 1], og[g]);
        og[g] = fmaf(sc[2], w2[g * 9 + k0 + 2], og[g]);
    }
}

// ---------- main: 2 pixels (j, j+1) per thread; weights via s_load ----------
__global__ __launch_bounds__(256) void seesaw_v4(
    const float* __restrict__ x,     // [B,3,H,W] fp32 (conv + mirror)
    const half4v* __restrict__ xp,   // [B,H,W] half4
    const float* __restrict__ w1, const float* __restrict__ b1,
    const float* __restrict__ w2, const float* __restrict__ b2,
    float* __restrict__ out)
{
    int t = threadIdx.x;
    int gid = blockIdx.x * 256 + t;
    int u  = gid & 255;             // column-pair index
    int j0 = u << 1;
    int i  = (gid >> 8) & 511;
    int b  = gid >> 17;

    const float*  xb = x  + (size_t)b * 3 * PLANE;
    const half4v* hb = xp + ((size_t)b << 18);

    // ---- 3x3 conv (pad=1) for both pixels; weights are uniform s_loads ----
    float accA[8], accB[8];
#pragma unroll
    for (int e = 0; e < 8; e++) { accA[e] = b1[e]; accB[e] = b1[e]; }

#pragma unroll
    for (int di = 0; di < 3; di++) {
        int y = i + di - 1;
        bool yv = (unsigned)y < (unsigned)HDIM;
        int yc = yv ? y : 0;
#pragma unroll
        for (int dx = 0; dx < 4; dx++) {
            int xc = j0 + dx - 1;
            bool xv = (unsigned)xc < (unsigned)WDIM;
            int xcc = xv ? xc : 0;
            int base = (yc << 9) + xcc;
            float v0 = xb[base];
            float v1 = xb[PLANE + base];
            float v2 = xb[2 * PLANE + base];
            if (!(yv && xv)) { v0 = 0.f; v1 = 0.f; v2 = 0.f; }
#pragma unroll
            for (int e = 0; e < 8; e++) {
                if (dx < 3) {
                    accA[e] = fmaf(v0, w1[e * 27 +      di * 3 + dx], accA[e]);
                    accA[e] = fmaf(v1, w1[e * 27 +  9 + di * 3 + dx], accA[e]);
                    accA[e] = fmaf(v2, w1[e * 27 + 18 + di * 3 + dx], accA[e]);
                }
                if (dx >= 1) {
                    accB[e] = fmaf(v0, w1[e * 27 +      di * 3 + dx - 1], accB[e]);
                    accB[e] = fmaf(v1, w1[e * 27 +  9 + di * 3 + dx - 1], accB[e]);
                    accB[e] = fmaf(v2, w1[e * 27 + 18 + di * 3 + dx - 1], accB[e]);
                }
            }
        }
    }

    // ---- sigmoid ----
    float sA[8], sB[8];
#pragma unroll
    for (int e = 0; e < 8; e++) {
        sA[e] = __builtin_amdgcn_rcpf(1.0f + __expf(-accA[e]));
        sB[e] = __builtin_amdgcn_rcpf(1.0f + __expf(-accB[e]));
    }

    const float inv511 = 1.0f / 511.0f;
    float bx  = (float)i * inv511;          // row-based gx (reference swap)
    float byA = (float)j0 * inv511;
    float byB = (float)(j0 + 1) * inv511;

    float ogA[3] = {0.f, 0.f, 0.f};
    float ogB[3] = {0.f, 0.f, 0.f};
    gather5(hb, w2, sA, bx, byA, ogA);
    gather5(hb, w2, sB, bx, byB, ogB);

    // ---- mirror points p=5..8: only pixel (0,0) of each image can contribute ----
    if ((i | u) == 0) {
#pragma unroll
        for (int p = 5; p < 9; p++) {
            float c0 = 2.0f - sA[2 * (p - 5)];
            float c1 = 2.0f - sA[2 * (p - 5) + 1];
            float ixf = fmaf(bx + c0, 256.0f, 255.5f);
            float iyf = fmaf(byA + c1, 256.0f, 255.5f);
            float ix0f = floorf(ixf), iy0f = floorf(iyf);
            float wx1 = ixf - ix0f, wy1 = iyf - iy0f;
            float wx0 = 1.f - wx1,  wy0 = 1.f - wy1;
            int ix0 = (int)ix0f, iy0 = (int)iy0f;
            float s0 = 0.f, s1 = 0.f, s2 = 0.f;
            for (int cy = 0; cy < 2; cy++) {
                int yc2 = iy0 + cy;
                if (yc2 < 0 || yc2 >= HDIM) continue;
                float wy = cy ? wy1 : wy0;
                for (int cx = 0; cx < 2; cx++) {
                    int xcc2 = ix0 + cx;
                    if (xcc2 < 0 || xcc2 >= WDIM) continue;
                    float wgt = wy * (cx ? wx1 : wx0);
                    int base = (yc2 << 9) + xcc2;
                    s0 = fmaf(xb[base],             wgt, s0);
                    s1 = fmaf(xb[PLANE + base],     wgt, s1);
                    s2 = fmaf(xb[2 * PLANE + base], wgt, s2);
                }
            }
            int g  = p / 3;
            int k0 = (p % 3) * 3;
            ogA[g] = fmaf(s0, w2[g * 9 + k0 + 0], ogA[g]);
            ogA[g] = fmaf(s1, w2[g * 9 + k0 + 1], ogA[g]);
            ogA[g] = fmaf(s2, w2[g * 9 + k0 + 2], ogA[g]);
        }
    }

    // ---- bias + relu + coalesced float2 stores ----
    size_t ob = (size_t)(b * 3) * PLANE + ((size_t)i << 9) + j0;
#pragma unroll
    for (int g = 0; g < 3; g++) {
        float va = ogA[g] + b2[g];
        float vb = ogB[g] + b2[g];
        float2 o2;
        o2.x = va > 0.f ? va : 0.f;
        o2.y = vb > 0.f ? vb : 0.f;
        *(float2*)(out + ob + (size_t)g * PLANE) = o2;
    }
}

// ---------- fallback (round-1 style) if ws too small ----------
__global__ __launch_bounds__(256) void seesaw_fused_v1(
    const float* __restrict__ x, const float* __restrict__ w1,
    const float* __restrict__ b1, const float* __restrict__ w2,
    const float* __restrict__ b2, float* __restrict__ out)
{
    int t = threadIdx.x;
    int gid = blockIdx.x * 256 + t;
    int j = gid & (WDIM - 1);
    int i = (gid >> 9) & (HDIM - 1);
    int b = gid >> 18;
    const float* xb = x + (size_t)b * 3 * PLANE;
    float acc[8];
#pragma unroll
    for (int e = 0; e < 8; e++) acc[e] = b1[e];
#pragma unroll
    for (int di = 0; di < 3; di++) {
        int y = i + di - 1;
        if (y < 0 || y >= HDIM) continue;
#pragma unroll
        for (int dj = 0; dj < 3; dj++) {
            int xc = j + dj - 1;
            if (xc < 0 || xc >= WDIM) continue;
            size_t base = (size_t)y * WDIM + xc;
#pragma unroll
            for (int c = 0; c < 3; c++) {
                float v = xb[(size_t)c * PLANE + base];
#pragma unroll
                for (int e = 0; e < 8; e++)
                    acc[e] = fmaf(v, w1[e * 27 + c * 9 + di * 3 + dj], acc[e]);
            }
        }
    }
    float s[8];
#pragma unroll
    for (int e = 0; e < 8; e++) s[e] = 1.0f / (1.0f + __expf(-acc[e]));
    const float inv511 = 1.0f / 511.0f;
    float bx = (float)i * inv511, by = (float)j * inv511;
    float og0 = 0.f, og1 = 0.f, og2 = 0.f;
#pragma unroll
    for (int p = 0; p < 9; p++) {
        float c0, c1;
        if (p < 4)       { c0 = s[2 * p];              c1 = s[2 * p + 1]; }
        else if (p == 4) { c0 = 0.f;                   c1 = 0.f; }
        else             { c0 = 2.0f - s[2 * (p - 5)]; c1 = 2.0f - s[2 * (p - 5) + 1]; }
        float ixf = (bx + c0) * 256.0f + 255.5f;
        float iyf = (by + c1) * 256.0f + 255.5f;
        float ix0f = floorf(ixf), iy0f = floorf(iyf);
        float wx1 = ixf - ix0f, wy1 = iyf - iy0f;
        float wx0 = 1.f - wx1,  wy0 = 1.f - wy1;
        int ix0 = (int)ix0f, iy0 = (int)iy0f;
        float s0 = 0.f, s1 = 0.f, s2 = 0.f;
#pragma unroll
        for (int cy = 0; cy < 2; cy++) {
            int yc = iy0 + cy;
            if (yc < 0 || yc >= HDIM) continue;
            float wy = cy ? wy1 : wy0;
#pragma unroll
            for (int cx = 0; cx < 2; cx++) {
                int xcc = ix0 + cx;
                if (xcc < 0 || xcc >= WDIM) continue;
                float wgt = wy * (cx ? wx1 : wx0);
                size_t base = (size_t)yc * WDIM + xcc;
                s0 = fmaf(xb[base],             wgt, s0);
                s1 = fmaf(xb[PLANE + base],     wgt, s1);
                s2 = fmaf(xb[2 * PLANE + base], wgt, s2);
            }
        }
        int g  = p / 3;
        int k0 = (p % 3) * 3;
        float* og = (g == 0) ? &og0 : (g == 1) ? &og1 : &og2;
        *og = fmaf(s0, w2[g * 9 + k0 + 0], *og);
        *og = fmaf(s1, w2[g * 9 + k0 + 1], *og);
        *og = fmaf(s2, w2[g * 9 + k0 + 2], *og);
    }
    size_t ob = (size_t)(b * 3) * PLANE + (size_t)i * WDIM + j;
    float v0 = og0 + b2[0], v1 = og1 + b2[1], v2 = og2 + b2[2];
    out[ob]             = v0 > 0.f ? v0 : 0.f;
    out[ob + PLANE]     = v1 > 0.f ? v1 : 0.f;
    out[ob + 2 * PLANE] = v2 > 0.f ? v2 : 0.f;
}

extern "C" void kernel_launch(void* const* d_in, const int* in_sizes, int n_in,
                              void* d_out, int out_size, void* d_ws, size_t ws_size,
                              hipStream_t stream) {
    const float* x  = (const float*)d_in[0];
    const float* w1 = (const float*)d_in[1];
    const float* b1 = (const float*)d_in[2];
    const float* w2 = (const float*)d_in[3];
    const float* b2 = (const float*)d_in[4];
    float* out = (float*)d_out;

    int total = BATCH * HDIM * WDIM;                 // 2,097,152
    size_t need = (size_t)total * 8 + 16;            // 16 MiB fp16x4 pack + pair-load pad

    if (ws_size >= need) {
        half8v* xp = (half8v*)d_ws;
        repack_h4<<<total / 2 / 256, 256, 0, stream>>>(x, xp);
        seesaw_v4<<<total / 2 / 256, 256, 0, stream>>>(x, (const half4v*)d_ws,
                                                       w1, b1, w2, b2, out);
    } else {
        seesaw_fused_v1<<<total / 256, 256, 0, stream>>>(x, w1, b1, w2, b2, out);
    }
}

// Round 5
// 137.788 us; speedup vs baseline: 2.1449x; 1.0096x over previous
//
#include <hip/hip_runtime.h>

#define BATCH 8
#define HDIM  512
#define WDIM  512
#define PLANE (HDIM * WDIM)

typedef _Float16 half2v __attribute__((ext_vector_type(2)));
typedef _Float16 half4v __attribute__((ext_vector_type(4)));
typedef _Float16 half8v __attribute__((ext_vector_type(8)));

// two adjacent texels (x0,x0+1), each (c0,c1),(c2,0) as half2 pairs; 16B
struct __align__(8) HQuad { half2v p0, p1, p2, p3; };

#if __has_builtin(__builtin_amdgcn_fdot2)
#define FDOT2(a, b, c) __builtin_amdgcn_fdot2((a), (b), (c), false)
#else
#define FDOT2(a, b, c) fmaf((float)(a).x, (float)(b).x, fmaf((float)(a).y, (float)(b).y, (c)))
#endif

// ---------- repack: NCHW fp32 -> [B,H,W] half4 (c0,c1,c2,0); 4 px/thread ----------
__global__ __launch_bounds__(256) void repack_h4w(
    const float* __restrict__ x,   // [B,3,H,W]
    half8v* __restrict__ xp)       // pairs of half4
{
    int gid = blockIdx.x * 256 + threadIdx.x;   // 4-pixel unit id
    int b = gid >> 16;                          // PLANE/4 = 65536 units per image
    int u = gid & 65535;
    const float* xb = x + (size_t)b * 3 * PLANE;
    int pix = u << 2;
    float4 a0 = *(const float4*)(xb + pix);
    float4 a1 = *(const float4*)(xb + PLANE + pix);
    float4 a2 = *(const float4*)(xb + 2 * PLANE + pix);
    half8v o0, o1;
    o0[0] = (_Float16)a0.x; o0[1] = (_Float16)a1.x; o0[2] = (_Float16)a2.x; o0[3] = (_Float16)0.f;
    o0[4] = (_Float16)a0.y; o0[5] = (_Float16)a1.y; o0[6] = (_Float16)a2.y; o0[7] = (_Float16)0.f;
    o1[0] = (_Float16)a0.z; o1[1] = (_Float16)a1.z; o1[2] = (_Float16)a2.z; o1[3] = (_Float16)0.f;
    o1[4] = (_Float16)a0.w; o1[5] = (_Float16)a1.w; o1[6] = (_Float16)a2.w; o1[7] = (_Float16)0.f;
    size_t base = (size_t)b * (PLANE / 2) + (size_t)u * 2;
    xp[base]     = o0;
    xp[base + 1] = o1;
}

// ---------- main: 2 pixels/thread; fused 10-point gather; fp16 dot epilogue ----------
__global__ __launch_bounds__(256) void seesaw_v5(
    const float* __restrict__ x,     // [B,3,H,W] fp32 (conv + mirror)
    const char* __restrict__ xpack,  // [B,H,W] half4 as bytes
    const float* __restrict__ w1, const float* __restrict__ b1,
    const float* __restrict__ w2, const float* __restrict__ b2,
    float* __restrict__ out)
{
    int t = threadIdx.x;
    int gid = blockIdx.x * 256 + t;
    int u  = gid & 255;             // column-pair index
    int j0 = u << 1;
    int i  = (gid >> 8) & 511;
    int b  = gid >> 17;

    const float* xb = x + (size_t)b * 3 * PLANE;
    const char*  hb = xpack + ((size_t)b << 21);   // PLANE * 8 bytes

    // ---- 3x3 conv (pad=1) for both pixels; weights via s_load ----
    float accA[8], accB[8];
#pragma unroll
    for (int e = 0; e < 8; e++) { accA[e] = b1[e]; accB[e] = b1[e]; }

#pragma unroll
    for (int di = 0; di < 3; di++) {
        int y = i + di - 1;
        bool yv = (unsigned)y < (unsigned)HDIM;
        int yc = yv ? y : 0;
#pragma unroll
        for (int dx = 0; dx < 4; dx++) {
            int xc = j0 + dx - 1;
            bool xv = (unsigned)xc < (unsigned)WDIM;
            int xcc = xv ? xc : 0;
            int base = (yc << 9) + xcc;
            float v0 = xb[base];
            float v1 = xb[PLANE + base];
            float v2 = xb[2 * PLANE + base];
            if (!(yv && xv)) { v0 = 0.f; v1 = 0.f; v2 = 0.f; }
#pragma unroll
            for (int e = 0; e < 8; e++) {
                if (dx < 3) {
                    accA[e] = fmaf(v0, w1[e * 27 +      di * 3 + dx], accA[e]);
                    accA[e] = fmaf(v1, w1[e * 27 +  9 + di * 3 + dx], accA[e]);
                    accA[e] = fmaf(v2, w1[e * 27 + 18 + di * 3 + dx], accA[e]);
                }
                if (dx >= 1) {
                    accB[e] = fmaf(v0, w1[e * 27 +      di * 3 + dx - 1], accB[e]);
                    accB[e] = fmaf(v1, w1[e * 27 +  9 + di * 3 + dx - 1], accB[e]);
                    accB[e] = fmaf(v2, w1[e * 27 + 18 + di * 3 + dx - 1], accB[e]);
                }
            }
        }
    }

    // ---- sigmoid ----
    float sA[8], sB[8];
#pragma unroll
    for (int e = 0; e < 8; e++) {
        sA[e] = __builtin_amdgcn_rcpf(1.0f + __expf(-accA[e]));
        sB[e] = __builtin_amdgcn_rcpf(1.0f + __expf(-accB[e]));
    }

    // ---- w2 rows packed to half2 (wave-uniform, once) ----
    half2v w2a[5], w2b[5];
#pragma unroll
    for (int q = 0; q < 5; q++) {
        w2a[q][0] = (_Float16)w2[q * 3];
        w2a[q][1] = (_Float16)w2[q * 3 + 1];
        w2b[q][0] = (_Float16)w2[q * 3 + 2];
        w2b[q][1] = (_Float16)0.f;
    }

    const float inv511 = 1.0f / 511.0f;
    float bx  = (float)i * inv511;          // row-based gx (reference swap)
    float byA = (float)j0 * inv511;
    float byB = (float)(j0 + 1) * inv511;

    // ---- phase 1: addresses + weights for all 10 points (both pixels) ----
    int   adr[10][2];
    float wY0[10], wY1[10], wX0[10], wX1[10];
#pragma unroll
    for (int q = 0; q < 10; q++) {
        int pp = q % 5;
        const float* sv = (q < 5) ? sA : sB;
        float by = (q < 5) ? byA : byB;
        float c0 = (pp < 4) ? sv[2 * pp]     : 0.0f;
        float c1 = (pp < 4) ? sv[2 * pp + 1] : 0.0f;
        float ixf = fmaf(bx + c0, 256.0f, 255.5f);   // ((gx+1)*512-1)*0.5
        float iyf = fmaf(by + c1, 256.0f, 255.5f);
        float ix0f = floorf(ixf);
        float iy0f = floorf(iyf);
        float wx1 = ixf - ix0f, wy1 = iyf - iy0f;
        float wx0 = 1.f - wx1,  wy0 = 1.f - wy1;
        int ix0 = (int)ix0f, iy0 = (int)iy0f;       // low side never <0

        float wx0v = (ix0 <= 511) ? wx0 : 0.f;
        float wx1v = (ix0 <= 510) ? wx1 : 0.f;
        float wy0v = (iy0 <= 511) ? wy0 : 0.f;
        float wy1v = (iy0 <= 510) ? wy1 : 0.f;
        int x0c = min(ix0, 511);
        int y0c = min(iy0, 511), y1c = min(iy0 + 1, 511);

        float wxs = wx0v + wx1v;
        wX0[q] = wx0v; wX1[q] = wx1v;
        wY0[q] = wy0v; wY1[q] = wy1v;
        adr[q][0] = (wy0v * wxs > 0.f) ? ((y0c << 9) + x0c) : 0;
        adr[q][1] = (wy1v * wxs > 0.f) ? ((y1c << 9) + x0c) : 0;
    }

    // ---- phase 2: all 20 pair-loads back-to-back ----
    HQuad qv[10][2];
#pragma unroll
    for (int q = 0; q < 10; q++) {
        qv[q][0] = *(const HQuad*)(hb + ((size_t)adr[q][0] << 3));
        qv[q][1] = *(const HQuad*)(hb + ((size_t)adr[q][1] << 3));
    }

    // ---- phase 3: fp16 dot per texel, bilinear combine into groups ----
    float og[2][3] = {{0.f, 0.f, 0.f}, {0.f, 0.f, 0.f}};
#pragma unroll
    for (int q = 0; q < 10; q++) {
        int pp = q % 5;
        int px = q / 5;
        int g  = pp / 3;            // 0,0,0,1,1
        float dl0 = FDOT2(qv[q][0].p0, w2a[pp], FDOT2(qv[q][0].p1, w2b[pp], 0.f));
        float dh0 = FDOT2(qv[q][0].p2, w2a[pp], FDOT2(qv[q][0].p3, w2b[pp], 0.f));
        float dl1 = FDOT2(qv[q][1].p0, w2a[pp], FDOT2(qv[q][1].p1, w2b[pp], 0.f));
        float dh1 = FDOT2(qv[q][1].p2, w2a[pp], FDOT2(qv[q][1].p3, w2b[pp], 0.f));
        float r0 = fmaf(dh0, wX1[q], dl0 * wX0[q]);
        float r1 = fmaf(dh1, wX1[q], dl1 * wX0[q]);
        og[px][g] = fmaf(r1, wY1[q], fmaf(r0, wY0[q], og[px][g]));
    }

    // ---- mirror points p=5..8: only pixel (0,0) of each image contributes ----
    if ((i | u) == 0) {
#pragma unroll
        for (int p = 5; p < 9; p++) {
            float c0 = 2.0f - sA[2 * (p - 5)];
            float c1 = 2.0f - sA[2 * (p - 5) + 1];
            float ixf = fmaf(bx + c0, 256.0f, 255.5f);
            float iyf = fmaf(byA + c1, 256.0f, 255.5f);
            float ix0f = floorf(ixf), iy0f = floorf(iyf);
            float wx1 = ixf - ix0f, wy1 = iyf - iy0f;
            float wx0 = 1.f - wx1,  wy0 = 1.f - wy1;
            int ix0 = (int)ix0f, iy0 = (int)iy0f;
            float s0 = 0.f, s1 = 0.f, s2 = 0.f;
            for (int cy = 0; cy < 2; cy++) {
                int yc2 = iy0 + cy;
                if (yc2 < 0 || yc2 >= HDIM) continue;
                float wy = cy ? wy1 : wy0;
                for (int cx = 0; cx < 2; cx++) {
                    int xcc2 = ix0 + cx;
                    if (xcc2 < 0 || xcc2 >= WDIM) continue;
                    float wgt = wy * (cx ? wx1 : wx0);
                    int base = (yc2 << 9) + xcc2;
                    s0 = fmaf(xb[base],             wgt, s0);
                    s1 = fmaf(xb[PLANE + base],     wgt, s1);
                    s2 = fmaf(xb[2 * PLANE + base], wgt, s2);
                }
            }
            int g  = p / 3;
            int k0 = (p % 3) * 3;
            og[0][g] = fmaf(s0, w2[g * 9 + k0 + 0], og[0][g]);
            og[0][g] = fmaf(s1, w2[g * 9 + k0 + 1], og[0][g]);
            og[0][g] = fmaf(s2, w2[g * 9 + k0 + 2], og[0][g]);
        }
    }

    // ---- bias + relu + coalesced float2 stores ----
    size_t ob = (size_t)(b * 3) * PLANE + ((size_t)i << 9) + j0;
#pragma unroll
    for (int g = 0; g < 3; g++) {
        float va = og[0][g] + b2[g];
        float vb = og[1][g] + b2[g];
        float2 o2;
        o2.x = va > 0.f ? va : 0.f;
        o2.y = vb > 0.f ? vb : 0.f;
        *(float2*)(out + ob + (size_t)g * PLANE) = o2;
    }
}

// ---------- fallback (round-1 style) if ws too small ----------
__global__ __launch_bounds__(256) void seesaw_fused_v1(
    const float* __restrict__ x, const float* __restrict__ w1,
    const float* __restrict__ b1, const float* __restrict__ w2,
    const float* __restrict__ b2, float* __restrict__ out)
{
    int t = threadIdx.x;
    int gid = blockIdx.x * 256 + t;
    int j = gid & (WDIM - 1);
    int i = (gid >> 9) & (HDIM - 1);
    int b = gid >> 18;
    const float* xb = x + (size_t)b * 3 * PLANE;
    float acc[8];
#pragma unroll
    for (int e = 0; e < 8; e++) acc[e] = b1[e];
#pragma unroll
    for (int di = 0; di < 3; di++) {
        int y = i + di - 1;
        if (y < 0 || y >= HDIM) continue;
#pragma unroll
        for (int dj = 0; dj < 3; dj++) {
            int xc = j + dj - 1;
            if (xc < 0 || xc >= WDIM) continue;
            size_t base = (size_t)y * WDIM + xc;
#pragma unroll
            for (int c = 0; c < 3; c++) {
                float v = xb[(size_t)c * PLANE + base];
#pragma unroll
                for (int e = 0; e < 8; e++)
                    acc[e] = fmaf(v, w1[e * 27 + c * 9 + di * 3 + dj], acc[e]);
            }
        }
    }
    float s[8];
#pragma unroll
    for (int e = 0; e < 8; e++) s[e] = 1.0f / (1.0f + __expf(-acc[e]));
    const float inv511 = 1.0f / 511.0f;
    float bx = (float)i * inv511, by = (float)j * inv511;
    float og0 = 0.f, og1 = 0.f, og2 = 0.f;
#pragma unroll
    for (int p = 0; p < 9; p++) {
        float c0, c1;
        if (p < 4)       { c0 = s[2 * p];              c1 = s[2 * p + 1]; }
        else if (p == 4) { c0 = 0.f;                   c1 = 0.f; }
        else             { c0 = 2.0f - s[2 * (p - 5)]; c1 = 2.0f - s[2 * (p - 5) + 1]; }
        float ixf = (bx + c0) * 256.0f + 255.5f;
        float iyf = (by + c1) * 256.0f + 255.5f;
        float ix0f = floorf(ixf), iy0f = floorf(iyf);
        float wx1 = ixf - ix0f, wy1 = iyf - iy0f;
        float wx0 = 1.f - wx1,  wy0 = 1.f - wy1;
        int ix0 = (int)ix0f, iy0 = (int)iy0f;
        float s0 = 0.f, s1 = 0.f, s2 = 0.f;
#pragma unroll
        for (int cy = 0; cy < 2; cy++) {
            int yc = iy0 + cy;
            if (yc < 0 || yc >= HDIM) continue;
            float wy = cy ? wy1 : wy0;
#pragma unroll
            for (int cx = 0; cx < 2; cx++) {
                int xcc = ix0 + cx;
                if (xcc < 0 || xcc >= WDIM) continue;
                float wgt = wy * (cx ? wx1 : wx0);
                size_t base = (size_t)yc * WDIM + xcc;
                s0 = fmaf(xb[base],             wgt, s0);
                s1 = fmaf(xb[PLANE + base],     wgt, s1);
                s2 = fmaf(xb[2 * PLANE + base], wgt, s2);
            }
        }
        int g  = p / 3;
        int k0 = (p % 3) * 3;
        float* og = (g == 0) ? &og0 : (g == 1) ? &og1 : &og2;
        *og = fmaf(s0, w2[g * 9 + k0 + 0], *og);
        *og = fmaf(s1, w2[g * 9 + k0 + 1], *og);
        *og = fmaf(s2, w2[g * 9 + k0 + 2], *og);
    }
    size_t ob = (size_t)(b * 3) * PLANE + (size_t)i * WDIM + j;
    float v0 = og0 + b2[0], v1 = og1 + b2[1], v2 = og2 + b2[2];
    out[ob]             = v0 > 0.f ? v0 : 0.f;
    out[ob + PLANE]     = v1 > 0.f ? v1 : 0.f;
    out[ob + 2 * PLANE] = v2 > 0.f ? v2 : 0.f;
}

extern "C" void kernel_launch(void* const* d_in, const int* in_sizes, int n_in,
                              void* d_out, int out_size, void* d_ws, size_t ws_size,
                              hipStream_t stream) {
    const float* x  = (const float*)d_in[0];
    const float* w1 = (const float*)d_in[1];
    const float* b1 = (const float*)d_in[2];
    const float* w2 = (const float*)d_in[3];
    const float* b2 = (const float*)d_in[4];
    float* out = (float*)d_out;

    int total = BATCH * HDIM * WDIM;                 // 2,097,152
    size_t need = (size_t)total * 8 + 16;            // 16 MiB fp16x4 pack + pair-load pad

    if (ws_size >= need) {
        repack_h4w<<<total / 4 / 256, 256, 0, stream>>>(x, (half8v*)d_ws);
        seesaw_v5<<<total / 2 / 256, 256, 0, stream>>>(x, (const char*)d_ws,
                                                       w1, b1, w2, b2, out);
    } else {
        seesaw_fused_v1<<<total / 256, 256, 0, stream>>>(x, w1, b1, w2, b2, out);
    }
}

// Round 6
// 129.396 us; speedup vs baseline: 2.2840x; 1.0649x over previous
//
#include <hip/hip_runtime.h>

#define BATCH 8
#define HDIM  512
#define WDIM  512
#define PLANE (HDIM * WDIM)

typedef _Float16 half2v __attribute__((ext_vector_type(2)));
typedef _Float16 half8v __attribute__((ext_vector_type(8)));

// two adjacent texels (x0,x0+1), each (c0,c1),(c2,0) as half2 pairs; 16B
struct __align__(8) HQuad { half2v p0, p1, p2, p3; };

#if __has_builtin(__builtin_amdgcn_fdot2)
#define FDOT2(a, b, c) __builtin_amdgcn_fdot2((a), (b), (c), false)
#else
#define FDOT2(a, b, c) fmaf((float)(a).x, (float)(b).x, fmaf((float)(a).y, (float)(b).y, (c)))
#endif

// ---------- repack: NCHW fp32 -> [B,H,W] half4 (c0,c1,c2,0); 4 px/thread ----------
__global__ __launch_bounds__(256) void repack_h4w(
    const float* __restrict__ x,   // [B,3,H,W]
    half8v* __restrict__ xp)       // pairs of half4
{
    int gid = blockIdx.x * 256 + threadIdx.x;   // 4-pixel unit id
    int b = gid >> 16;                          // PLANE/4 = 65536 units per image
    int u = gid & 65535;
    const float* xb = x + (size_t)b * 3 * PLANE;
    int pix = u << 2;
    float4 a0 = *(const float4*)(xb + pix);
    float4 a1 = *(const float4*)(xb + PLANE + pix);
    float4 a2 = *(const float4*)(xb + 2 * PLANE + pix);
    half8v o0, o1;
    o0[0] = (_Float16)a0.x; o0[1] = (_Float16)a1.x; o0[2] = (_Float16)a2.x; o0[3] = (_Float16)0.f;
    o0[4] = (_Float16)a0.y; o0[5] = (_Float16)a1.y; o0[6] = (_Float16)a2.y; o0[7] = (_Float16)0.f;
    o1[0] = (_Float16)a0.z; o1[1] = (_Float16)a1.z; o1[2] = (_Float16)a2.z; o1[3] = (_Float16)0.f;
    o1[4] = (_Float16)a0.w; o1[5] = (_Float16)a1.w; o1[6] = (_Float16)a2.w; o1[7] = (_Float16)0.f;
    size_t base = (size_t)b * (PLANE / 2) + (size_t)u * 2;
    xp[base]     = o0;
    xp[base + 1] = o1;
}

// ---------- main: 1 px/thread; XCD-swizzled (image = blockIdx&7) ----------
__global__ __launch_bounds__(256) void seesaw_v6(
    const float* __restrict__ x,     // [B,3,H,W] fp32 (conv + mirror)
    const char* __restrict__ xpack,  // [B,H,W] half4 as bytes
    const float* __restrict__ w1, const float* __restrict__ b1,
    const float* __restrict__ w2, const float* __restrict__ b2,
    float* __restrict__ out)
{
    int t = threadIdx.x;
    // XCD swizzle: blocks of image b land on XCD b (blockIdx%8 -> XCD heuristic).
    // 8192 blocks: img = blk&7, intra-slice = blk>>3 in [0,1024).
    int b     = blockIdx.x & 7;
    int intra = blockIdx.x >> 3;
    int pix   = intra * 256 + t;     // [0, PLANE)
    int j = pix & 511;
    int i = pix >> 9;

    const float* xb = x + (size_t)b * 3 * PLANE;
    const char*  hb = xpack + ((size_t)b << 21);   // PLANE * 8 bytes

    // ---- 3x3 conv (pad=1); weights via s_load; branchless edge handling ----
    float acc[8];
#pragma unroll
    for (int e = 0; e < 8; e++) acc[e] = b1[e];

#pragma unroll
    for (int di = 0; di < 3; di++) {
        int y = i + di - 1;
        bool yv = (unsigned)y < (unsigned)HDIM;
        int yc = yv ? y : 0;
#pragma unroll
        for (int dj = 0; dj < 3; dj++) {
            int xc = j + dj - 1;
            bool xv = (unsigned)xc < (unsigned)WDIM;
            int xcc = xv ? xc : 0;
            int base = (yc << 9) + xcc;
            float v0 = xb[base];
            float v1 = xb[PLANE + base];
            float v2 = xb[2 * PLANE + base];
            if (!(yv && xv)) { v0 = 0.f; v1 = 0.f; v2 = 0.f; }
#pragma unroll
            for (int e = 0; e < 8; e++) {
                acc[e] = fmaf(v0, w1[e * 27 +      di * 3 + dj], acc[e]);
                acc[e] = fmaf(v1, w1[e * 27 +  9 + di * 3 + dj], acc[e]);
                acc[e] = fmaf(v2, w1[e * 27 + 18 + di * 3 + dj], acc[e]);
            }
        }
    }

    // ---- sigmoid ----
    float s[8];
#pragma unroll
    for (int e = 0; e < 8; e++)
        s[e] = __builtin_amdgcn_rcpf(1.0f + __expf(-acc[e]));

    // ---- w2 rows packed to half2 (wave-uniform) ----
    half2v w2a[5], w2b[5];
#pragma unroll
    for (int q = 0; q < 5; q++) {
        w2a[q][0] = (_Float16)w2[q * 3];
        w2a[q][1] = (_Float16)w2[q * 3 + 1];
        w2b[q][0] = (_Float16)w2[q * 3 + 2];
        w2b[q][1] = (_Float16)0.f;
    }

    const float inv511 = 1.0f / 511.0f;
    float bx = (float)i * inv511;   // feeds gx (reference swaps axes)
    float by = (float)j * inv511;   // feeds gy

    // ---- phase 1: addresses + weights for 5 points ----
    int   adr[5][2];
    float wY0[5], wY1[5], wX0[5], wX1[5];
#pragma unroll
    for (int q = 0; q < 5; q++) {
        float c0 = (q < 4) ? s[2 * q]     : 0.0f;
        float c1 = (q < 4) ? s[2 * q + 1] : 0.0f;
        float ixf = fmaf(bx + c0, 256.0f, 255.5f);   // ((gx+1)*512-1)*0.5
        float iyf = fmaf(by + c1, 256.0f, 255.5f);
        float ix0f = floorf(ixf);
        float iy0f = floorf(iyf);
        float wx1 = ixf - ix0f, wy1 = iyf - iy0f;
        float wx0 = 1.f - wx1,  wy0 = 1.f - wy1;
        int ix0 = (int)ix0f, iy0 = (int)iy0f;       // low side never <0

        float wx0v = (ix0 <= 511) ? wx0 : 0.f;
        float wx1v = (ix0 <= 510) ? wx1 : 0.f;
        float wy0v = (iy0 <= 511) ? wy0 : 0.f;
        float wy1v = (iy0 <= 510) ? wy1 : 0.f;
        int x0c = min(ix0, 511);
        int y0c = min(iy0, 511), y1c = min(iy0 + 1, 511);

        float wxs = wx0v + wx1v;
        wX0[q] = wx0v; wX1[q] = wx1v;
        wY0[q] = wy0v; wY1[q] = wy1v;
        // dead rows -> broadcast address 0 (single line, no scatter)
        adr[q][0] = (wy0v * wxs > 0.f) ? ((y0c << 9) + x0c) : 0;
        adr[q][1] = (wy1v * wxs > 0.f) ? ((y1c << 9) + x0c) : 0;
    }

    // ---- phase 2: all 10 pair-loads back-to-back (max MLP) ----
    HQuad qv[5][2];
#pragma unroll
    for (int q = 0; q < 5; q++) {
        qv[q][0] = *(const HQuad*)(hb + ((size_t)adr[q][0] << 3));
        qv[q][1] = *(const HQuad*)(hb + ((size_t)adr[q][1] << 3));
    }

    // ---- phase 3: fp16 dot per texel, bilinear combine into groups ----
    float og[3] = {0.f, 0.f, 0.f};
#pragma unroll
    for (int q = 0; q < 5; q++) {
        int g = q / 3;              // 0,0,0,1,1
        float dl0 = FDOT2(qv[q][0].p0, w2a[q], FDOT2(qv[q][0].p1, w2b[q], 0.f));
        float dh0 = FDOT2(qv[q][0].p2, w2a[q], FDOT2(qv[q][0].p3, w2b[q], 0.f));
        float dl1 = FDOT2(qv[q][1].p0, w2a[q], FDOT2(qv[q][1].p1, w2b[q], 0.f));
        float dh1 = FDOT2(qv[q][1].p2, w2a[q], FDOT2(qv[q][1].p3, w2b[q], 0.f));
        float r0 = fmaf(dh0, wX1[q], dl0 * wX0[q]);
        float r1 = fmaf(dh1, wX1[q], dl1 * wX0[q]);
        og[g] = fmaf(r1, wY1[q], fmaf(r0, wY0[q], og[g]));
    }

    // ---- mirror points p=5..8: only pixel (0,0) of each image contributes ----
    if ((i | j) == 0) {
#pragma unroll
        for (int p = 5; p < 9; p++) {
            float c0 = 2.0f - s[2 * (p - 5)];
            float c1 = 2.0f - s[2 * (p - 5) + 1];
            float ixf = fmaf(bx + c0, 256.0f, 255.5f);
            float iyf = fmaf(by + c1, 256.0f, 255.5f);
            float ix0f = floorf(ixf), iy0f = floorf(iyf);
            float wx1 = ixf - ix0f, wy1 = iyf - iy0f;
            float wx0 = 1.f - wx1,  wy0 = 1.f - wy1;
            int ix0 = (int)ix0f, iy0 = (int)iy0f;
            float s0 = 0.f, s1 = 0.f, s2 = 0.f;
            for (int cy = 0; cy < 2; cy++) {
                int yc2 = iy0 + cy;
                if (yc2 < 0 || yc2 >= HDIM) continue;
                float wy = cy ? wy1 : wy0;
                for (int cx = 0; cx < 2; cx++) {
                    int xcc2 = ix0 + cx;
                    if (xcc2 < 0 || xcc2 >= WDIM) continue;
                    float wgt = wy * (cx ? wx1 : wx0);
                    int base = (yc2 << 9) + xcc2;
                    s0 = fmaf(xb[base],             wgt, s0);
                    s1 = fmaf(xb[PLANE + base],     wgt, s1);
                    s2 = fmaf(xb[2 * PLANE + base], wgt, s2);
                }
            }
            int g  = p / 3;
            int k0 = (p % 3) * 3;
            og[g] = fmaf(s0, w2[g * 9 + k0 + 0], og[g]);
            og[g] = fmaf(s1, w2[g * 9 + k0 + 1], og[g]);
            og[g] = fmaf(s2, w2[g * 9 + k0 + 2], og[g]);
        }
    }

    // ---- bias + relu + store (j-coalesced) ----
    size_t ob = (size_t)(b * 3) * PLANE + ((size_t)i << 9) + j;
#pragma unroll
    for (int g = 0; g < 3; g++) {
        float v = og[g] + b2[g];
        out[ob + (size_t)g * PLANE] = v > 0.f ? v : 0.f;
    }
}

// ---------- fallback (round-1 style) if ws too small ----------
__global__ __launch_bounds__(256) void seesaw_fused_v1(
    const float* __restrict__ x, const float* __restrict__ w1,
    const float* __restrict__ b1, const float* __restrict__ w2,
    const float* __restrict__ b2, float* __restrict__ out)
{
    int t = threadIdx.x;
    int gid = blockIdx.x * 256 + t;
    int j = gid & (WDIM - 1);
    int i = (gid >> 9) & (HDIM - 1);
    int b = gid >> 18;
    const float* xb = x + (size_t)b * 3 * PLANE;
    float acc[8];
#pragma unroll
    for (int e = 0; e < 8; e++) acc[e] = b1[e];
#pragma unroll
    for (int di = 0; di < 3; di++) {
        int y = i + di - 1;
        if (y < 0 || y >= HDIM) continue;
#pragma unroll
        for (int dj = 0; dj < 3; dj++) {
            int xc = j + dj - 1;
            if (xc < 0 || xc >= WDIM) continue;
            size_t base = (size_t)y * WDIM + xc;
#pragma unroll
            for (int c = 0; c < 3; c++) {
                float v = xb[(size_t)c * PLANE + base];
#pragma unroll
                for (int e = 0; e < 8; e++)
                    acc[e] = fmaf(v, w1[e * 27 + c * 9 + di * 3 + dj], acc[e]);
            }
        }
    }
    float s[8];
#pragma unroll
    for (int e = 0; e < 8; e++) s[e] = 1.0f / (1.0f + __expf(-acc[e]));
    const float inv511 = 1.0f / 511.0f;
    float bx = (float)i * inv511, by = (float)j * inv511;
    float og0 = 0.f, og1 = 0.f, og2 = 0.f;
#pragma unroll
    for (int p = 0; p < 9; p++) {
        float c0, c1;
        if (p < 4)       { c0 = s[2 * p];              c1 = s[2 * p + 1]; }
        else if (p == 4) { c0 = 0.f;                   c1 = 0.f; }
        else             { c0 = 2.0f - s[2 * (p - 5)]; c1 = 2.0f - s[2 * (p - 5) + 1]; }
        float ixf = (bx + c0) * 256.0f + 255.5f;
        float iyf = (by + c1) * 256.0f + 255.5f;
        float ix0f = floorf(ixf), iy0f = floorf(iyf);
        float wx1 = ixf - ix0f, wy1 = iyf - iy0f;
        float wx0 = 1.f - wx1,  wy0 = 1.f - wy1;
        int ix0 = (int)ix0f, iy0 = (int)iy0f;
        float s0 = 0.f, s1 = 0.f, s2 = 0.f;
#pragma unroll
        for (int cy = 0; cy < 2; cy++) {
            int yc = iy0 + cy;
            if (yc < 0 || yc >= HDIM) continue;
            float wy = cy ? wy1 : wy0;
#pragma unroll
            for (int cx = 0; cx < 2; cx++) {
                int xcc = ix0 + cx;
                if (xcc < 0 || xcc >= WDIM) continue;
                float wgt = wy * (cx ? wx1 : wx0);
                size_t base = (size_t)yc * WDIM + xcc;
                s0 = fmaf(xb[base],             wgt, s0);
                s1 = fmaf(xb[PLANE + base],     wgt, s1);
                s2 = fmaf(xb[2 * PLANE + base], wgt, s2);
            }
        }
        int g  = p / 3;
        int k0 = (p % 3) * 3;
        float* og = (g == 0) ? &og0 : (g == 1) ? &og1 : &og2;
        *og = fmaf(s0, w2[g * 9 + k0 + 0], *og);
        *og = fmaf(s1, w2[g * 9 + k0 + 1], *og);
        *og = fmaf(s2, w2[g * 9 + k0 + 2], *og);
    }
    size_t ob = (size_t)(b * 3) * PLANE + (size_t)i * WDIM + j;
    float v0 = og0 + b2[0], v1 = og1 + b2[1], v2 = og2 + b2[2];
    out[ob]             = v0 > 0.f ? v0 : 0.f;
    out[ob + PLANE]     = v1 > 0.f ? v1 : 0.f;
    out[ob + 2 * PLANE] = v2 > 0.f ? v2 : 0.f;
}

extern "C" void kernel_launch(void* const* d_in, const int* in_sizes, int n_in,
                              void* d_out, int out_size, void* d_ws, size_t ws_size,
                              hipStream_t stream) {
    const float* x  = (const float*)d_in[0];
    const float* w1 = (const float*)d_in[1];
    const float* b1 = (const float*)d_in[2];
    const float* w2 = (const float*)d_in[3];
    const float* b2 = (const float*)d_in[4];
    float* out = (float*)d_out;

    int total = BATCH * HDIM * WDIM;                 // 2,097,152
    size_t need = (size_t)total * 8 + 16;            // 16 MiB fp16x4 pack + pair-load pad

    if (ws_size >= need) {
        repack_h4w<<<total / 4 / 256, 256, 0, stream>>>(x, (half8v*)d_ws);
        seesaw_v6<<<total / 256, 256, 0, stream>>>(x, (const char*)d_ws,
                                                   w1, b1, w2, b2, out);
    } else {
        seesaw_fused_v1<<<total / 256, 256, 0, stream>>>(x, w1, b1, w2, b2, out);
    }
}

// Round 7
// 128.743 us; speedup vs baseline: 2.2956x; 1.0051x over previous
//
#include <hip/hip_runtime.h>

#define BATCH 8
#define HDIM  512
#define WDIM  512
#define PLANE (HDIM * WDIM)

typedef _Float16 half2v __attribute__((ext_vector_type(2)));
typedef _Float16 half8v __attribute__((ext_vector_type(8)));

// two adjacent texels (x0,x0+1), each (c0,c1),(c2,0) as half2 pairs; 16B
struct __align__(8) HQuad { half2v p0, p1, p2, p3; };

#if __has_builtin(__builtin_amdgcn_fdot2)
#define FDOT2(a, b, c) __builtin_amdgcn_fdot2((a), (b), (c), false)
#else
#define FDOT2(a, b, c) fmaf((float)(a).x, (float)(b).x, fmaf((float)(a).y, (float)(b).y, (c)))
#endif

// ---------- repack: NCHW fp32 -> [B,H,W] half4; XCD-swizzled (img = blk&7) ----------
__global__ __launch_bounds__(256) void repack_h4x(
    const float* __restrict__ x,   // [B,3,H,W]
    half8v* __restrict__ xp)       // pairs of half4
{
    int b = blockIdx.x & 7;
    int u = (blockIdx.x >> 3) * 256 + threadIdx.x;   // [0, PLANE/4)
    const float* xb = x + (size_t)b * 3 * PLANE;
    int pix = u << 2;
    float4 a0 = *(const float4*)(xb + pix);
    float4 a1 = *(const float4*)(xb + PLANE + pix);
    float4 a2 = *(const float4*)(xb + 2 * PLANE + pix);
    half8v o0, o1;
    o0[0] = (_Float16)a0.x; o0[1] = (_Float16)a1.x; o0[2] = (_Float16)a2.x; o0[3] = (_Float16)0.f;
    o0[4] = (_Float16)a0.y; o0[5] = (_Float16)a1.y; o0[6] = (_Float16)a2.y; o0[7] = (_Float16)0.f;
    o1[0] = (_Float16)a0.z; o1[1] = (_Float16)a1.z; o1[2] = (_Float16)a2.z; o1[3] = (_Float16)0.f;
    o1[4] = (_Float16)a0.w; o1[5] = (_Float16)a1.w; o1[6] = (_Float16)a2.w; o1[7] = (_Float16)0.f;
    size_t base = (size_t)b * (PLANE / 2) + (size_t)u * 2;
    xp[base]     = o0;
    xp[base + 1] = o1;
}

// ---------- main: 1 px/thread; scalar row bases; XCD-swizzled ----------
__global__ __launch_bounds__(256) void seesaw_v7(
    const float* __restrict__ x,     // [B,3,H,W] fp32 (conv + mirror)
    const char* __restrict__ xpack,  // [B,H,W] half4 as bytes
    const float* __restrict__ w1, const float* __restrict__ b1,
    const float* __restrict__ w2, const float* __restrict__ b2,
    float* __restrict__ out)
{
    int t = threadIdx.x;
    int b    = blockIdx.x & 7;           // image -> XCD locality
    int rest = blockIdx.x >> 3;          // [0, 1024)
    int i    = rest >> 1;                // SCALAR row (block covers half a row)
    int j    = ((rest & 1) << 8) + t;    // 0..511

    const float* xb = x + (size_t)b * 3 * PLANE;
    const char*  hb = xpack + ((size_t)b << 21);   // PLANE * 8 bytes

    // ---- 3x3 conv (pad=1); scalar row-base addressing ----
    float acc[8];
#pragma unroll
    for (int e = 0; e < 8; e++) acc[e] = b1[e];

    // shared per-lane column indices (clamped); edge lanes zero via cndmask
    int cm1 = j - 1; if (cm1 < 0) cm1 = 0;
    int cp1 = j + 1; if (cp1 > 511) cp1 = 511;
    bool jlo = (j == 0), jhi = (j == 511);

    if (i >= 1 && i <= 510) {            // scalar branch: interior rows, no y clamp
#pragma unroll
        for (int di = 0; di < 3; di++) {
            const float* row = xb + ((i + di - 1) << 9);   // scalar base
#pragma unroll
            for (int c = 0; c < 3; c++) {
                const float* rc = row + c * PLANE;         // scalar base
                float vm = rc[cm1]; if (jlo) vm = 0.f;
                float v0 = rc[j];
                float vp = rc[cp1]; if (jhi) vp = 0.f;
#pragma unroll
                for (int e = 0; e < 8; e++) {
                    const float* we = &w1[e * 27 + c * 9 + di * 3];
                    acc[e] = fmaf(vm, we[0], acc[e]);
                    acc[e] = fmaf(v0, we[1], acc[e]);
                    acc[e] = fmaf(vp, we[2], acc[e]);
                }
            }
        }
    } else {                              // 16 of 8192 blocks: y-edge rows
#pragma unroll
        for (int di = 0; di < 3; di++) {
            int y = i + di - 1;
            bool yv = (unsigned)y < (unsigned)HDIM;
            const float* row = xb + ((yv ? y : 0) << 9);
#pragma unroll
            for (int c = 0; c < 3; c++) {
                const float* rc = row + c * PLANE;
                float vm = rc[cm1]; if (jlo || !yv) vm = 0.f;
                float v0 = rc[j];   if (!yv)        v0 = 0.f;
                float vp = rc[cp1]; if (jhi || !yv) vp = 0.f;
#pragma unroll
                for (int e = 0; e < 8; e++) {
                    const float* we = &w1[e * 27 + c * 9 + di * 3];
                    acc[e] = fmaf(vm, we[0], acc[e]);
                    acc[e] = fmaf(v0, we[1], acc[e]);
                    acc[e] = fmaf(vp, we[2], acc[e]);
                }
            }
        }
    }

    // ---- sigmoid, pre-scaled by 256 ----
    float s256[8];
#pragma unroll
    for (int e = 0; e < 8; e++)
        s256[e] = 256.0f * __builtin_amdgcn_rcpf(1.0f + __expf(-acc[e]));

    // ---- w2 rows packed to half2 (wave-uniform) ----
    half2v w2a[5], w2b[5];
#pragma unroll
    for (int q = 0; q < 5; q++) {
        w2a[q][0] = (_Float16)w2[q * 3];
        w2a[q][1] = (_Float16)w2[q * 3 + 1];
        w2b[q][0] = (_Float16)w2[q * 3 + 2];
        w2b[q][1] = (_Float16)0.f;
    }

    const float k511 = 256.0f / 511.0f;
    float fxb = fmaf((float)i, k511, 255.5f);   // scalar-ish; feeds gx (axis swap)
    float fyb = fmaf((float)j, k511, 255.5f);

    // ---- phase 1: addresses + weights for 5 points ----
    int   adr[5][2];
    float wY0[5], wY1[5], wX0[5], wX1[5];
#pragma unroll
    for (int q = 0; q < 5; q++) {
        float ixf = (q < 4) ? (fxb + s256[2 * q])     : fxb;
        float iyf = (q < 4) ? (fyb + s256[2 * q + 1]) : fyb;
        float wx1 = ixf - truncf(ixf);              // positive -> fract
        float wy1 = iyf - truncf(iyf);
        int ix0 = (int)ixf, iy0 = (int)iyf;         // trunc == floor (positive)
        float wx0 = 1.f - wx1, wy0 = 1.f - wy1;

        float wx0v = (ix0 <= 511) ? wx0 : 0.f;
        float wx1v = (ix0 <= 510) ? wx1 : 0.f;
        float wy0v = (iy0 <= 511) ? wy0 : 0.f;
        float wy1v = (iy0 <= 510) ? wy1 : 0.f;
        int x0c = min(ix0, 511);
        int y0c = min(iy0, 511), y1c = min(iy0 + 1, 511);

        float wxs = wx0v + wx1v;
        wX0[q] = wx0v; wX1[q] = wx1v;
        wY0[q] = wy0v; wY1[q] = wy1v;
        adr[q][0] = (wy0v * wxs > 0.f) ? ((y0c << 9) + x0c) : 0;
        adr[q][1] = (wy1v * wxs > 0.f) ? ((y1c << 9) + x0c) : 0;
    }

    // ---- phase 2: all 10 pair-loads back-to-back ----
    HQuad qv[5][2];
#pragma unroll
    for (int q = 0; q < 5; q++) {
        qv[q][0] = *(const HQuad*)(hb + ((size_t)adr[q][0] << 3));
        qv[q][1] = *(const HQuad*)(hb + ((size_t)adr[q][1] << 3));
    }

    // ---- phase 3: fp16 dot per texel, bilinear combine ----
    float og[3] = {0.f, 0.f, 0.f};
#pragma unroll
    for (int q = 0; q < 5; q++) {
        int g = q / 3;              // 0,0,0,1,1
        float dl0 = FDOT2(qv[q][0].p0, w2a[q], FDOT2(qv[q][0].p1, w2b[q], 0.f));
        float dh0 = FDOT2(qv[q][0].p2, w2a[q], FDOT2(qv[q][0].p3, w2b[q], 0.f));
        float dl1 = FDOT2(qv[q][1].p0, w2a[q], FDOT2(qv[q][1].p1, w2b[q], 0.f));
        float dh1 = FDOT2(qv[q][1].p2, w2a[q], FDOT2(qv[q][1].p3, w2b[q], 0.f));
        float r0 = fmaf(dh0, wX1[q], dl0 * wX0[q]);
        float r1 = fmaf(dh1, wX1[q], dl1 * wX0[q]);
        og[g] = fmaf(r1, wY1[q], fmaf(r0, wY0[q], og[g]));
    }

    // ---- mirror points p=5..8: only pixel (0,0) of each image contributes ----
    if ((i | j) == 0) {
#pragma unroll
        for (int p = 5; p < 9; p++) {
            float ixf = fxb + 512.0f - s256[2 * (p - 5)];
            float iyf = fyb + 512.0f - s256[2 * (p - 5) + 1];
            float ix0f = floorf(ixf), iy0f = floorf(iyf);
            float wx1 = ixf - ix0f, wy1 = iyf - iy0f;
            float wx0 = 1.f - wx1,  wy0 = 1.f - wy1;
            int ix0 = (int)ix0f, iy0 = (int)iy0f;
            float s0 = 0.f, s1 = 0.f, s2 = 0.f;
            for (int cy = 0; cy < 2; cy++) {
                int yc2 = iy0 + cy;
                if (yc2 < 0 || yc2 >= HDIM) continue;
                float wy = cy ? wy1 : wy0;
                for (int cx = 0; cx < 2; cx++) {
                    int xcc2 = ix0 + cx;
                    if (xcc2 < 0 || xcc2 >= WDIM) continue;
                    float wgt = wy * (cx ? wx1 : wx0);
                    int base = (yc2 << 9) + xcc2;
                    s0 = fmaf(xb[base],             wgt, s0);
                    s1 = fmaf(xb[PLANE + base],     wgt, s1);
                    s2 = fmaf(xb[2 * PLANE + base], wgt, s2);
                }
            }
            int g  = p / 3;
            int k0 = (p % 3) * 3;
            og[g] = fmaf(s0, w2[g * 9 + k0 + 0], og[g]);
            og[g] = fmaf(s1, w2[g * 9 + k0 + 1], og[g]);
            og[g] = fmaf(s2, w2[g * 9 + k0 + 2], og[g]);
        }
    }

    // ---- bias + relu + store (scalar base + j) ----
    const float* dummy = xb;  // keep xb alive for mirror path
    (void)dummy;
    size_t ob = (size_t)(b * 3) * PLANE + ((size_t)i << 9) + j;
#pragma unroll
    for (int g = 0; g < 3; g++) {
        float v = og[g] + b2[g];
        out[ob + (size_t)g * PLANE] = v > 0.f ? v : 0.f;
    }
}

// ---------- fallback (round-1 style) if ws too small ----------
__global__ __launch_bounds__(256) void seesaw_fused_v1(
    const float* __restrict__ x, const float* __restrict__ w1,
    const float* __restrict__ b1, const float* __restrict__ w2,
    const float* __restrict__ b2, float* __restrict__ out)
{
    int t = threadIdx.x;
    int gid = blockIdx.x * 256 + t;
    int j = gid & (WDIM - 1);
    int i = (gid >> 9) & (HDIM - 1);
    int b = gid >> 18;
    const float* xb = x + (size_t)b * 3 * PLANE;
    float acc[8];
#pragma unroll
    for (int e = 0; e < 8; e++) acc[e] = b1[e];
#pragma unroll
    for (int di = 0; di < 3; di++) {
        int y = i + di - 1;
        if (y < 0 || y >= HDIM) continue;
#pragma unroll
        for (int dj = 0; dj < 3; dj++) {
            int xc = j + dj - 1;
            if (xc < 0 || xc >= WDIM) continue;
            size_t base = (size_t)y * WDIM + xc;
#pragma unroll
            for (int c = 0; c < 3; c++) {
                float v = xb[(size_t)c * PLANE + base];
#pragma unroll
                for (int e = 0; e < 8; e++)
                    acc[e] = fmaf(v, w1[e * 27 + c * 9 + di * 3 + dj], acc[e]);
            }
        }
    }
    float s[8];
#pragma unroll
    for (int e = 0; e < 8; e++) s[e] = 1.0f / (1.0f + __expf(-acc[e]));
    const float inv511 = 1.0f / 511.0f;
    float bx = (float)i * inv511, by = (float)j * inv511;
    float og0 = 0.f, og1 = 0.f, og2 = 0.f;
#pragma unroll
    for (int p = 0; p < 9; p++) {
        float c0, c1;
        if (p < 4)       { c0 = s[2 * p];              c1 = s[2 * p + 1]; }
        else if (p == 4) { c0 = 0.f;                   c1 = 0.f; }
        else             { c0 = 2.0f - s[2 * (p - 5)]; c1 = 2.0f - s[2 * (p - 5) + 1]; }
        float ixf = (bx + c0) * 256.0f + 255.5f;
        float iyf = (by + c1) * 256.0f + 255.5f;
        float ix0f = floorf(ixf), iy0f = floorf(iyf);
        float wx1 = ixf - ix0f, wy1 = iyf - iy0f;
        float wx0 = 1.f - wx1,  wy0 = 1.f - wy1;
        int ix0 = (int)ix0f, iy0 = (int)iy0f;
        float s0 = 0.f, s1 = 0.f, s2 = 0.f;
#pragma unroll
        for (int cy = 0; cy < 2; cy++) {
            int yc = iy0 + cy;
            if (yc < 0 || yc >= HDIM) continue;
            float wy = cy ? wy1 : wy0;
#pragma unroll
            for (int cx = 0; cx < 2; cx++) {
                int xcc = ix0 + cx;
                if (xcc < 0 || xcc >= WDIM) continue;
                float wgt = wy * (cx ? wx1 : wx0);
                size_t base = (size_t)yc * WDIM + xcc;
                s0 = fmaf(xb[base],             wgt, s0);
                s1 = fmaf(xb[PLANE + base],     wgt, s1);
                s2 = fmaf(xb[2 * PLANE + base], wgt, s2);
            }
        }
        int g  = p / 3;
        int k0 = (p % 3) * 3;
        float* og = (g == 0) ? &og0 : (g == 1) ? &og1 : &og2;
        *og = fmaf(s0, w2[g * 9 + k0 + 0], *og);
        *og = fmaf(s1, w2[g * 9 + k0 + 1], *og);
        *og = fmaf(s2, w2[g * 9 + k0 + 2], *og);
    }
    size_t ob = (size_t)(b * 3) * PLANE + (size_t)i * WDIM + j;
    float v0 = og0 + b2[0], v1 = og1 + b2[1], v2 = og2 + b2[2];
    out[ob]             = v0 > 0.f ? v0 : 0.f;
    out[ob + PLANE]     = v1 > 0.f ? v1 : 0.f;
    out[ob + 2 * PLANE] = v2 > 0.f ? v2 : 0.f;
}

extern "C" void kernel_launch(void* const* d_in, const int* in_sizes, int n_in,
                              void* d_out, int out_size, void* d_ws, size_t ws_size,
                              hipStream_t stream) {
    const float* x  = (const float*)d_in[0];
    const float* w1 = (const float*)d_in[1];
    const float* b1 = (const float*)d_in[2];
    const float* w2 = (const float*)d_in[3];
    const float* b2 = (const float*)d_in[4];
    float* out = (float*)d_out;

    int total = BATCH * HDIM * WDIM;                 // 2,097,152
    size_t need = (size_t)total * 8 + 16;            // 16 MiB fp16x4 pack + pair-load pad

    if (ws_size >= need) {
        repack_h4x<<<total / 4 / 256, 256, 0, stream>>>(x, (half8v*)d_ws);
        seesaw_v7<<<total / 256, 256, 0, stream>>>(x, (const char*)d_ws,
                                                   w1, b1, w2, b2, out);
    } else {
        seesaw_fused_v1<<<total / 256, 256, 0, stream>>>(x, w1, b1, w2, b2, out);
    }
}